// Round 6
// baseline (260.063 us; speedup 1.0000x reference)
//
#include <hip/hip_runtime.h>
#include <hip/hip_bf16.h>

#define NN 100000
#define NE 1600000
#define D  128
#define NPAD 100352           // 392 * 256 = 196 * 512
#define NBLK 782              // ceil(NN / 128)
#define CAP  64               // max in-degree bucket (Poisson(16): P(>=64)~8e-20)

// coarse partition params
#define BSH    9              // bucket = dest >> 9  (512 nodes/bucket)
#define NB_C   196            // NPAD >> 9
#define CAPB   9216           // bucket arena capacity (mean 8163, +11 sigma)
#define PCHUNK 2048           // edges per partition block
#define PEPT   8              // edges per thread
#define NPART  782            // ceil(NE / PCHUNK)

// k_agg slice params
#define NSL    8              // 8 column slices of 16 bf16 (32 B) each
#define NGRP   3125           // 100000 / 32 dests per chunk
#define AGG_BLOCKS 2048       // fully-resident grid: 8 blocks/CU, 32 waves/CU

typedef __attribute__((ext_vector_type(8))) short short8;
typedef __attribute__((ext_vector_type(4))) float floatx4;
typedef __attribute__((ext_vector_type(2))) float fx2;
typedef __attribute__((ext_vector_type(4))) int intx4;

__device__ __forceinline__ unsigned short f2b(float f) {
    __hip_bfloat16 h = __float2bfloat16(f);   // RNE
    return *(unsigned short*)&h;
}

// LDS tile swizzle for [128 rows][128 bf16] (256 B rows): XOR 16 B-granule
// index with (row&7) -- G4 pattern. In ushort units: col ^ ((row&7)<<3).
__device__ __forceinline__ int swz(int row, int col_us) {
    return row * 128 + (col_us ^ ((row & 7) << 3));
}

// -------------------------------------- coarse partition (196 buckets) ----
__global__ __launch_bounds__(256) void k_part(const int* __restrict__ row,
                                              const int* __restrict__ col,
                                              int* __restrict__ bcnt,
                                              unsigned int* __restrict__ edgesP) {
    __shared__ int cur[NB_C], basep[NB_C];
    int t = threadIdx.x;
    size_t e0 = (size_t)blockIdx.x * PCHUNK;

    for (int i = t; i < NB_C; i += 256) cur[i] = 0;
    __syncthreads();

    unsigned int val[PEPT];
    int bk[PEPT], rk[PEPT];
#pragma unroll
    for (int i = 0; i < PEPT; ++i) {
        size_t e = e0 + i * 256 + t;
        bk[i] = -1;
        if (e < NE) {
            int r = row[e], c = col[e];
            if (r != c) {                      // existing self-loops weight 0
                bk[i]  = c >> BSH;
                val[i] = (unsigned)r | ((unsigned)(c & 511) << 17);
                rk[i]  = atomicAdd(&cur[bk[i]], 1);   // LDS atomic
            }
        }
    }
    __syncthreads();

    for (int i = t; i < NB_C; i += 256)
        basep[i] = cur[i] ? atomicAdd(&bcnt[i], cur[i]) : 0;
    __syncthreads();

#pragma unroll
    for (int i = 0; i < PEPT; ++i) {
        if (bk[i] >= 0) {
            int pos = basep[bk[i]] + rk[i];
            if (pos < CAPB) edgesP[(size_t)bk[i] * CAPB + pos] = val[i];
        }
    }
}

// ------------------------------------------ fine fill (1 block/bucket) ----
__global__ __launch_bounds__(1024) void k_fine(const int* __restrict__ bcnt,
                                               const unsigned int* __restrict__ edgesP,
                                               int* __restrict__ counts,
                                               float* __restrict__ dinv,
                                               int* __restrict__ srcs) {
    __shared__ int cnt[512];
    int t = threadIdx.x, b = blockIdx.x;
    int n0 = b << BSH;
    for (int i = t; i < 512; i += 1024) cnt[i] = 0;
    __syncthreads();

    int m = min(bcnt[b], CAPB);
    const unsigned int* ep = edgesP + (size_t)b * CAPB;
    for (int i = t; i < m; i += 1024) {
        unsigned int v = ep[i];
        int c0 = v >> 17;                     // dest & 511
        int s  = v & 0x1FFFF;                 // src
        int pos = atomicAdd(&cnt[c0], 1);     // LDS atomic
        if (pos < CAP) srcs[(size_t)(n0 + c0) * CAP + pos] = s;
    }
    __syncthreads();
    for (int i = t; i < 512; i += 1024) {
        int n = n0 + i;
        int cv = cnt[i];
        counts[n] = min(cv, CAP);
        dinv[n] = rsqrtf((float)cv + 1.0f);   // +1 appended self-loop (true degree)
    }
}

// --------------------------------------------- W^T convert (fp32 -> bf16) ----
// Writes wt in the SWIZZLED layout so k_gemm's linear LDS copy + swizzled
// fragment reads are consistent.
__global__ void k_prep_w(const float* __restrict__ w, unsigned short* __restrict__ wt) {
    int i = blockIdx.x * 256 + threadIdx.x;   // over 128*128
    int n = i >> 7, k = i & 127;
    wt[swz(n, k)] = f2b(w[k * D + n]);
}

// --------------------------------- bf16 MFMA GEMM: yw = bf16(dinv .* (x W)) ----
// 128x128 block tile, 4 waves in 64x64 quadrants, mfma_f32_16x16x32_bf16.
// Output now written in SLICE-MAJOR layout yw_sliced[slice][node][16 bf16]
// (slice = col>>4): each 3.2 MB slice is contiguous -> fits one XCD L2 for
// the sliced k_agg.
__global__ __launch_bounds__(256, 2) void k_gemm_mfma(const float* __restrict__ x,
                                                      const unsigned short* __restrict__ wt,
                                                      const float* __restrict__ dinv,
                                                      unsigned short* __restrict__ yw) {
    __shared__ unsigned short sX[128 * 128];   // 32 KB bf16 x-tile (swizzled)
    __shared__ unsigned short sW[128 * 128];   // 32 KB bf16 W^T (swizzled)
    __shared__ float sD[128];
    int tid = threadIdx.x;
    long row0 = (long)blockIdx.x * 128;

    if (tid < 128) {
        long gr = row0 + tid;
        sD[tid] = (gr < NN) ? dinv[gr] : 0.0f;
    }
    {
        const uint4* src = (const uint4*)wt;
        uint4* dst = (uint4*)sW;
#pragma unroll
        for (int j = 0; j < 8; ++j) dst[tid + j * 256] = src[tid + j * 256];
    }
#pragma unroll
    for (int j = 0; j < 16; ++j) {
        int i = tid + j * 256;
        int r = i >> 5, q = i & 31;            // row r, 8 B chunk q (4 ushorts)
        floatx4 v = {0.f, 0.f, 0.f, 0.f};
        long gr = row0 + r;
        if (gr < NN) v = __builtin_nontemporal_load((const floatx4*)(x + gr * D + q * 4));
        ushort4 u;
        u.x = f2b(v.x); u.y = f2b(v.y); u.z = f2b(v.z); u.w = f2b(v.w);
        *(ushort4*)&sX[swz(r, q * 4)] = u;
    }
    __syncthreads();

    int lane = tid & 63, wave = tid >> 6;
    int wm = (wave & 1) * 64, wn = (wave >> 1) * 64;
    int lrow = lane & 15, lkb = (lane >> 4) * 8;

    floatx4 acc[4][4] = {};
#pragma unroll
    for (int kc = 0; kc < 4; ++kc) {
        int kb = kc * 32 + lkb;
        short8 bfr[4];
#pragma unroll
        for (int tn = 0; tn < 4; ++tn)
            bfr[tn] = *(const short8*)&sW[swz(wn + tn * 16 + lrow, kb)];
#pragma unroll
        for (int tm = 0; tm < 4; ++tm) {
            short8 afr = *(const short8*)&sX[swz(wm + tm * 16 + lrow, kb)];
#pragma unroll
            for (int tn = 0; tn < 4; ++tn)
                acc[tm][tn] = __builtin_amdgcn_mfma_f32_16x16x32_bf16(afr, bfr[tn], acc[tm][tn], 0, 0, 0);
        }
    }

    int orow = (lane >> 4) * 4;
    int ocol = lane & 15;
    int wb = wn >> 4;                          // base slice of this wave (0 or 4)
#pragma unroll
    for (int tm = 0; tm < 4; ++tm) {
#pragma unroll
        for (int reg = 0; reg < 4; ++reg) {
            int  rt = wm + tm * 16 + orow + reg;
            long m  = row0 + rt;
            if (m < NN) {
                float dm = sD[rt];
                // slice-major: col = wn + ocol + tn*16 -> slice wb+tn, in-slice ocol
                unsigned short* o = yw + ((size_t)wb * NN + m) * 16 + ocol;
#pragma unroll
                for (int tn = 0; tn < 4; ++tn)
                    o[(size_t)tn * NN * 16] = f2b(acc[tm][tn][reg] * dm);
            }
        }
    }
}

// --------------------------------- per-node aggregate, XCD-sliced ----
// yw pinned at ~3.9 TB/s L2-miss refill (r1/r3: MLP depth and 4x instr
// reduction both null) -> L2-capacity bound: 25.6 MB working set vs 4 MB
// per-XCD L2. Fix: slice-major yw (8 x 3.2 MB contiguous slices); block
// slice = blockIdx&7 rides the round-robin block->XCD mapping; grid is
// FULLY RESIDENT (2048 blocks = 8/CU, 32 waves/CU) so the mapping is
// stable; grid-stride over dest chunks. After warmup each XCD's gathers
// are L2 hits. Src lists staged per-chunk to LDS via nontemporal loads
// (no L2 pollution); wave = 8 dests x 8 lanes, lane j owns cols 2j,2j+1.
__global__ __launch_bounds__(256, 8) void k_agg(const int* __restrict__ counts,
                                                const int* __restrict__ srcs,
                                                const float* __restrict__ dinv,
                                                const unsigned int* __restrict__ ywd,
                                                const float* __restrict__ bias,
                                                float* __restrict__ out) {
    __shared__ int slds[32 * 40];              // 32 dests x 32 srcs, stride 40 dwords
    int tid = threadIdx.x;
    int w = tid >> 6;                          // wave 0..3
    int d = (tid >> 3) & 7;                    // dest-in-wave 0..7
    int j = tid & 7;                           // col-dword 0..7 (cols 2j,2j+1)
    int din = w * 8 + d;                       // dest-in-block 0..31
    int sl = blockIdx.x & 7;                   // slice -> XCD (round-robin)

    const unsigned int* ywj = ywd + (size_t)sl * NN * 8 + j;
    fx2 b2 = *(const fx2*)(bias + sl * 16 + 2 * j);

    // stage indices: thread covers srcs[(c0+r)*CAP + q*4 .. +3]
    int r = tid >> 3, q = tid & 7;

    for (int grp = blockIdx.x >> 3; grp < NGRP; grp += AGG_BLOCKS / 8) {
        int c0 = grp * 32;
        {   // stage first 32 srcs of 32 dests (nt: one-touch, no L2 pollution)
            intx4 v = __builtin_nontemporal_load(
                (const intx4*)(srcs + (size_t)(c0 + r) * CAP + q * 4));
            *(intx4*)&slds[r * 40 + q * 4] = v;
        }
        __syncthreads();

        int c = c0 + din;
        int cnt = counts[c];                   // already capped at CAP
        float dc = dinv[c];
        const int* srow = slds + din * 40;

        unsigned int v0 = ywj[(size_t)c * 8];  // self-loop term
        float a0 = __uint_as_float(v0 << 16);
        float a1 = __uint_as_float(v0 & 0xFFFF0000u);

        int lim = min(cnt, 32);
        int p = 0;
        for (; p + 4 <= lim; p += 4) {
            intx4 s4 = *(const intx4*)(srow + p);
            unsigned int g0 = ywj[(size_t)s4.x * 8];
            unsigned int g1 = ywj[(size_t)s4.y * 8];
            unsigned int g2 = ywj[(size_t)s4.z * 8];
            unsigned int g3 = ywj[(size_t)s4.w * 8];
            a0 += __uint_as_float(g0 << 16);  a1 += __uint_as_float(g0 & 0xFFFF0000u);
            a0 += __uint_as_float(g1 << 16);  a1 += __uint_as_float(g1 & 0xFFFF0000u);
            a0 += __uint_as_float(g2 << 16);  a1 += __uint_as_float(g2 & 0xFFFF0000u);
            a0 += __uint_as_float(g3 << 16);  a1 += __uint_as_float(g3 & 0xFFFF0000u);
        }
        for (; p < lim; ++p) {
            unsigned int g = ywj[(size_t)srow[p] * 8];
            a0 += __uint_as_float(g << 16);  a1 += __uint_as_float(g & 0xFFFF0000u);
        }
        if (cnt > 32) {                        // rare tail (P ~ 2e-4 per node)
            const int* sp2 = srcs + (size_t)c * CAP;
            for (p = 32; p < cnt; ++p) {
                unsigned int g = ywj[(size_t)sp2[p] * 8];
                a0 += __uint_as_float(g << 16);  a1 += __uint_as_float(g & 0xFFFF0000u);
            }
        }

        fx2 o;
        o.x = dc * a0 + b2.x;
        o.y = dc * a1 + b2.y;
        __builtin_nontemporal_store(o, (fx2*)(out + (size_t)c * D + sl * 16 + 2 * j));
        __syncthreads();                       // before next chunk restages slds
    }
}

// ---------------------------------------------------------------- launch ----
extern "C" void kernel_launch(void* const* d_in, const int* in_sizes, int n_in,
                              void* d_out, int out_size, void* d_ws, size_t ws_size,
                              hipStream_t stream) {
    const float* x    = (const float*)d_in[0];
    const int*   ei   = (const int*)d_in[1];      // [2, NE] (int32 on device)
    const float* w    = (const float*)d_in[2];
    const float* bias = (const float*)d_in[3];
    float*       out  = (float*)d_out;

    const int* row = ei;
    const int* col = ei + NE;

    // ws layout (~52 MB, 16B-aligned segments):
    int*   counts = (int*)d_ws;                          // NPAD
    float* dinv   = (float*)(counts + NPAD);             // NPAD
    int*   srcs   = (int*)(dinv + NPAD);                 // NN*CAP   (25.6 MB)
    unsigned short* yw = (unsigned short*)(srcs + (size_t)NN * CAP);  // NN*D bf16, slice-major
    unsigned short* wt = yw + (size_t)NN * D;            // 128*128 bf16
    int*   bcnt   = (int*)(wt + 128 * 128);              // NB_C
    // edgesP (196*9216 u32 = 7.2 MB) aliases yw: dead before k_gemm_mfma runs
    unsigned int* edgesP = (unsigned int*)yw;

    hipMemsetAsync(bcnt, 0, NB_C * sizeof(int), stream);

    k_prep_w<<<64, 256, 0, stream>>>(w, wt);
    k_part<<<NPART, 256, 0, stream>>>(row, col, bcnt, edgesP);
    k_fine<<<NB_C, 1024, 0, stream>>>(bcnt, edgesP, counts, dinv, srcs);
    k_gemm_mfma<<<NBLK, 256, 0, stream>>>(x, wt, dinv, yw);
    k_agg<<<AGG_BLOCKS, 256, 0, stream>>>(counts, srcs, dinv, (const unsigned int*)yw, bias, out);
}

// Round 7
// 226.357 us; speedup vs baseline: 1.1489x; 1.1489x over previous
//
#include <hip/hip_runtime.h>
#include <hip/hip_bf16.h>

#define NN 100000
#define NE 1600000
#define D  128
#define NPAD 100352           // 392 * 256 = 196 * 512
#define NBLK 782              // ceil(NN / 128)
#define CAP  64               // max in-degree bucket (Poisson(16): P(>=64)~8e-20)

// coarse partition params
#define BSH    9              // bucket = dest >> 9  (512 nodes/bucket)
#define NB_C   196            // NPAD >> 9
#define CAPB   9216           // bucket arena capacity (mean 8163, +11 sigma)
#define PCHUNK 2048           // edges per partition block
#define PEPT   8              // edges per thread
#define NPART  782            // ceil(NE / PCHUNK)

typedef __attribute__((ext_vector_type(8))) short short8;
typedef __attribute__((ext_vector_type(4))) float floatx4;
typedef __attribute__((ext_vector_type(4))) unsigned int uintx4;

__device__ __forceinline__ unsigned short f2b(float f) {
    __hip_bfloat16 h = __float2bfloat16(f);   // RNE
    return *(unsigned short*)&h;
}

// unpack one uintx4 (8 bf16) and accumulate into 8 fp32 lane-local slots
__device__ __forceinline__ void acc8(float (&a)[8], uintx4 v) {
    a[0] += __uint_as_float(v.x << 16);
    a[1] += __uint_as_float(v.x & 0xFFFF0000u);
    a[2] += __uint_as_float(v.y << 16);
    a[3] += __uint_as_float(v.y & 0xFFFF0000u);
    a[4] += __uint_as_float(v.z << 16);
    a[5] += __uint_as_float(v.z & 0xFFFF0000u);
    a[6] += __uint_as_float(v.w << 16);
    a[7] += __uint_as_float(v.w & 0xFFFF0000u);
}

// LDS tile swizzle for [128 rows][128 bf16] (256 B rows): XOR 16 B-granule
// index with (row&7) -- G4 pattern. In ushort units: col ^ ((row&7)<<3).
__device__ __forceinline__ int swz(int row, int col_us) {
    return row * 128 + (col_us ^ ((row & 7) << 3));
}

// -------------------------------------- coarse partition (196 buckets) ----
__global__ __launch_bounds__(256) void k_part(const int* __restrict__ row,
                                              const int* __restrict__ col,
                                              int* __restrict__ bcnt,
                                              unsigned int* __restrict__ edgesP) {
    __shared__ int cur[NB_C], basep[NB_C];
    int t = threadIdx.x;
    size_t e0 = (size_t)blockIdx.x * PCHUNK;

    for (int i = t; i < NB_C; i += 256) cur[i] = 0;
    __syncthreads();

    unsigned int val[PEPT];
    int bk[PEPT], rk[PEPT];
#pragma unroll
    for (int i = 0; i < PEPT; ++i) {
        size_t e = e0 + i * 256 + t;
        bk[i] = -1;
        if (e < NE) {
            int r = row[e], c = col[e];
            if (r != c) {                      // existing self-loops weight 0
                bk[i]  = c >> BSH;
                val[i] = (unsigned)r | ((unsigned)(c & 511) << 17);
                rk[i]  = atomicAdd(&cur[bk[i]], 1);   // LDS atomic
            }
        }
    }
    __syncthreads();

    for (int i = t; i < NB_C; i += 256)
        basep[i] = cur[i] ? atomicAdd(&bcnt[i], cur[i]) : 0;
    __syncthreads();

#pragma unroll
    for (int i = 0; i < PEPT; ++i) {
        if (bk[i] >= 0) {
            int pos = basep[bk[i]] + rk[i];
            if (pos < CAPB) edgesP[(size_t)bk[i] * CAPB + pos] = val[i];
        }
    }
}

// ------------------------------------------ fine fill (1 block/bucket) ----
__global__ __launch_bounds__(1024) void k_fine(const int* __restrict__ bcnt,
                                               const unsigned int* __restrict__ edgesP,
                                               int* __restrict__ counts,
                                               float* __restrict__ dinv,
                                               int* __restrict__ srcs) {
    __shared__ int cnt[512];
    int t = threadIdx.x, b = blockIdx.x;
    int n0 = b << BSH;
    for (int i = t; i < 512; i += 1024) cnt[i] = 0;
    __syncthreads();

    int m = min(bcnt[b], CAPB);
    const unsigned int* ep = edgesP + (size_t)b * CAPB;
    for (int i = t; i < m; i += 1024) {
        unsigned int v = ep[i];
        int c0 = v >> 17;                     // dest & 511
        int s  = v & 0x1FFFF;                 // src
        int pos = atomicAdd(&cnt[c0], 1);     // LDS atomic
        if (pos < CAP) srcs[(size_t)(n0 + c0) * CAP + pos] = s;
    }
    __syncthreads();
    for (int i = t; i < 512; i += 1024) {
        int n = n0 + i;
        int cv = cnt[i];
        counts[n] = min(cv, CAP);
        dinv[n] = rsqrtf((float)cv + 1.0f);   // +1 appended self-loop (true degree)
    }
}

// --------------------------------------------- W^T convert (fp32 -> bf16) ----
// Writes wt in the SWIZZLED layout so k_gemm's linear LDS copy + swizzled
// fragment reads are consistent.
__global__ void k_prep_w(const float* __restrict__ w, unsigned short* __restrict__ wt) {
    int i = blockIdx.x * 256 + threadIdx.x;   // over 128*128
    int n = i >> 7, k = i & 127;
    wt[swz(n, k)] = f2b(w[k * D + n]);
}

// --------------------------------- bf16 MFMA GEMM: yw = bf16(dinv .* (x W)) ----
// 128x128 block tile, 4 waves in 64x64 quadrants, mfma_f32_16x16x32_bf16.
// A frag:  A[m = lane&15][k = (lane>>4)*8 + j]      <- sX row-major [m][k]
// B frag:  B[k = (lane>>4)*8 + j][n = lane&15]      <- sW = W^T [n][k]
// C/D:     col = lane&15, row = (lane>>4)*4 + reg   (m89-verified mapping)
// Both LDS tiles XOR-swizzled (r5, confirmed win). NEW (r7): epilogue no
// longer issues 64 scalar 2-B global stores per lane (12.5M store instrs
// grid-wide); C-tile is staged into the dead sX buffer (same swizzle) and
// flushed with coalesced b128 LDS reads + dwordx4 global stores.
__global__ __launch_bounds__(256, 2) void k_gemm_mfma(const float* __restrict__ x,
                                                      const unsigned short* __restrict__ wt,
                                                      const float* __restrict__ dinv,
                                                      unsigned short* __restrict__ yw) {
    __shared__ unsigned short sX[128 * 128];   // 32 KB bf16 x-tile (swizzled); reused for C
    __shared__ unsigned short sW[128 * 128];   // 32 KB bf16 W^T (swizzled)
    __shared__ float sD[128];
    int tid = threadIdx.x;
    long row0 = (long)blockIdx.x * 128;

    if (tid < 128) {
        long gr = row0 + tid;
        sD[tid] = (gr < NN) ? dinv[gr] : 0.0f;
    }
    {
        const uint4* src = (const uint4*)wt;
        uint4* dst = (uint4*)sW;
#pragma unroll
        for (int j = 0; j < 8; ++j) dst[tid + j * 256] = src[tid + j * 256];
    }
#pragma unroll
    for (int j = 0; j < 16; ++j) {
        int i = tid + j * 256;
        int r = i >> 5, q = i & 31;            // row r, 8 B chunk q (4 ushorts)
        floatx4 v = {0.f, 0.f, 0.f, 0.f};
        long gr = row0 + r;
        if (gr < NN) v = __builtin_nontemporal_load((const floatx4*)(x + gr * D + q * 4));
        ushort4 u;
        u.x = f2b(v.x); u.y = f2b(v.y); u.z = f2b(v.z); u.w = f2b(v.w);
        *(ushort4*)&sX[swz(r, q * 4)] = u;
    }
    __syncthreads();

    int lane = tid & 63, wave = tid >> 6;
    int wm = (wave & 1) * 64, wn = (wave >> 1) * 64;
    int lrow = lane & 15, lkb = (lane >> 4) * 8;

    floatx4 acc[4][4] = {};
#pragma unroll
    for (int kc = 0; kc < 4; ++kc) {
        int kb = kc * 32 + lkb;
        short8 bfr[4];
#pragma unroll
        for (int tn = 0; tn < 4; ++tn)
            bfr[tn] = *(const short8*)&sW[swz(wn + tn * 16 + lrow, kb)];
#pragma unroll
        for (int tm = 0; tm < 4; ++tm) {
            short8 afr = *(const short8*)&sX[swz(wm + tm * 16 + lrow, kb)];
#pragma unroll
            for (int tn = 0; tn < 4; ++tn)
                acc[tm][tn] = __builtin_amdgcn_mfma_f32_16x16x32_bf16(afr, bfr[tn], acc[tm][tn], 0, 0, 0);
        }
    }

    // ---- epilogue: stage C into sX (swizzled), flush coalesced ----
    __syncthreads();                           // all waves done reading sX/sW

    int orow = (lane >> 4) * 4;
    int ocol = lane & 15;
#pragma unroll
    for (int tm = 0; tm < 4; ++tm) {
#pragma unroll
        for (int reg = 0; reg < 4; ++reg) {
            int rt = wm + tm * 16 + orow + reg;
            float dm = sD[rt];
#pragma unroll
            for (int tn = 0; tn < 4; ++tn)
                sX[swz(rt, wn + tn * 16 + ocol)] = f2b(acc[tm][tn][reg] * dm);
        }
    }
    __syncthreads();

    // flush: 2048 granules of 16 B; thread i covers granule (r = i>>4, cg = i&15)
#pragma unroll
    for (int j = 0; j < 8; ++j) {
        int i = tid + j * 256;
        int r = i >> 4, cg = i & 15;
        long gr = row0 + r;
        if (gr < NN) {
            uint4 v = *(const uint4*)&sX[swz(r, cg * 8)];
            *(uint4*)(yw + gr * D + cg * 8) = v;
        }
    }
}

// --------------------------------------- per-node aggregate, wave/dest ----
// r3/r5 champion (restored): dwordx4 gather -- each wave-instruction moves
// FOUR 256 B yw rows (lane group g=lane>>4 owns source p+g; lane f=lane&15
// holds a 16 B row slice). Pinned at ~3.9 TB/s L2-miss fabric for this
// random-256B pattern (r1/r3: MLP depth and 4x instr reduction both null;
// r6: XCD-sliced variant cut FETCH 3x but lockstep barriers + divergence
// regressed time 63->99 us -- structure parked for redesign).
__global__ __launch_bounds__(256) void k_agg(const int* __restrict__ counts,
                                             const int* __restrict__ srcs,
                                             const float* __restrict__ dinv,
                                             const uintx4* __restrict__ yw4,
                                             const float* __restrict__ bias,
                                             float* __restrict__ out) {
    int lane = threadIdx.x & 63;
    int c = blockIdx.x * 4 + (threadIdx.x >> 6);
    int g = lane >> 4, f = lane & 15;

    // effective source list: [c (self), srcs[0..cnt0-1]], cnt0 capped at 63
    int cnt0 = min(counts[c], 63);
    const int* sp = srcs + (size_t)c * CAP;
    int mysrc = c;
    if (lane >= 1 && lane <= cnt0) mysrc = __builtin_nontemporal_load(sp + lane - 1);
    int ec = cnt0 + 1;

    float dc = dinv[c];

    float a[8] = {0.f, 0.f, 0.f, 0.f, 0.f, 0.f, 0.f, 0.f};

    int p = 0;
    for (; p + 16 <= ec; p += 16) {
        uintx4 v[4];
#pragma unroll
        for (int i = 0; i < 4; ++i) {
            int s = __shfl(mysrc, p + i * 4 + g);
            v[i] = yw4[(size_t)s * 16 + f];
        }
#pragma unroll
        for (int i = 0; i < 4; ++i) acc8(a, v[i]);
    }
    if (p + 8 <= ec) {
        uintx4 v[2];
#pragma unroll
        for (int i = 0; i < 2; ++i) {
            int s = __shfl(mysrc, p + i * 4 + g);
            v[i] = yw4[(size_t)s * 16 + f];
        }
#pragma unroll
        for (int i = 0; i < 2; ++i) acc8(a, v[i]);
        p += 8;
    }
    if (p + 4 <= ec) {
        int s = __shfl(mysrc, p + g);
        uintx4 v = yw4[(size_t)s * 16 + f];
        acc8(a, v);
        p += 4;
    }
    int r = ec - p;                            // 0..3 remaining
    if (r > 0) {
        int s = __shfl(mysrc, p + ((g < r) ? g : 0));
        uintx4 v = yw4[(size_t)s * 16 + f];
        if (g < r) acc8(a, v);
    }

    // combine the 4 group-partials: lanes {f, f+16, f+32, f+48} -> full sum
#pragma unroll
    for (int j = 0; j < 8; ++j) a[j] += __shfl_xor(a[j], 16);
#pragma unroll
    for (int j = 0; j < 8; ++j) a[j] += __shfl_xor(a[j], 32);

    if (g == 0) {                              // lanes 0-15 store the row
        const floatx4* b4 = (const floatx4*)bias;
        floatx4 b0 = b4[f * 2], b1 = b4[f * 2 + 1];
        floatx4 o0, o1;
        o0.x = dc * a[0] + b0.x;  o0.y = dc * a[1] + b0.y;
        o0.z = dc * a[2] + b0.z;  o0.w = dc * a[3] + b0.w;
        o1.x = dc * a[4] + b1.x;  o1.y = dc * a[5] + b1.y;
        o1.z = dc * a[6] + b1.z;  o1.w = dc * a[7] + b1.w;
        floatx4* op = (floatx4*)(out + (size_t)c * D + f * 8);
        __builtin_nontemporal_store(o0, op);
        __builtin_nontemporal_store(o1, op + 1);
    }
}

// ---------------------------------------------------------------- launch ----
extern "C" void kernel_launch(void* const* d_in, const int* in_sizes, int n_in,
                              void* d_out, int out_size, void* d_ws, size_t ws_size,
                              hipStream_t stream) {
    const float* x    = (const float*)d_in[0];
    const int*   ei   = (const int*)d_in[1];      // [2, NE] (int32 on device)
    const float* w    = (const float*)d_in[2];
    const float* bias = (const float*)d_in[3];
    float*       out  = (float*)d_out;

    const int* row = ei;
    const int* col = ei + NE;

    // ws layout (~52 MB, 16B-aligned segments):
    int*   counts = (int*)d_ws;                          // NPAD
    float* dinv   = (float*)(counts + NPAD);             // NPAD
    int*   srcs   = (int*)(dinv + NPAD);                 // NN*CAP   (25.6 MB)
    unsigned short* yw = (unsigned short*)(srcs + (size_t)NN * CAP);  // NN*D bf16 (25.6 MB)
    unsigned short* wt = yw + (size_t)NN * D;            // 128*128 bf16
    int*   bcnt   = (int*)(wt + 128 * 128);              // NB_C
    // edgesP (196*9216 u32 = 7.2 MB) aliases yw: dead before k_gemm_mfma runs
    unsigned int* edgesP = (unsigned int*)yw;

    hipMemsetAsync(bcnt, 0, NB_C * sizeof(int), stream);

    k_prep_w<<<64, 256, 0, stream>>>(w, wt);
    k_part<<<NPART, 256, 0, stream>>>(row, col, bcnt, edgesP);
    k_fine<<<NB_C, 1024, 0, stream>>>(bcnt, edgesP, counts, dinv, srcs);
    k_gemm_mfma<<<NBLK, 256, 0, stream>>>(x, wt, dinv, yw);
    k_agg<<<NN / 4, 256, 0, stream>>>(counts, srcs, dinv, (const uintx4*)yw, bias, out);
}